// Round 10
// baseline (547.136 us; speedup 1.0000x reference)
//
#include <hip/hip_runtime.h>

// ClusterDiceLoss: segmented dice over 64 clusters of a 256^3 volume.
// 201 MB read-only. R3..R12: TEN structures, all 72-81 us (best R5 72.8 us
//   = 2.77 TB/s delivered). Invariant to: LDS layout/atomics/DS-op count,
//   global-atomic contention, MLP depth 2..24 (forced asm), occupancy
//   27..80%, block channel-phase, stream time-phase at constant MLP (R12),
//   and memory source (L3-warm == HBM-cold). Conclusion: per-CU consumption
//   floor ~4.4 B/cyc (~173 cyc per {wave-load-group + wave-histogram-op}).
//   All scatter-free histogram schemes priced WORSE (ballot ~600 cyc/64el
//   SALU-bound; MFMA one-hot ~250 cyc/32el + fragment build; broadcast
//   transpose = DS-bound again). Main loop is at its measured floor.
// R13: stop optimizing the loop; cut measured-stream overhead. Fuse the
//   finalize into the main kernel via last-block ticket (R11 PROVED this
//   correct, absmax=0; its regression was the stagger schedule, reverted).
//   Main loop = R5's exact best-measured structure (72.8 us).

#define NSEG 65          // clusters 0..64 (0 = background, dropped)
#define NREP 64          // replicated global partial slots
#define REP_MASK 63
#define NCOPY 16         // LDS histogram copies (one per 16 lanes)
#define BLOCKS 2048
#define THREADS 256
#define UNROLL 8

// Per-element u32 contribution: inter<<20 | sp<<10 | st.
// Bounds per LDS copy: 16 lanes x 32 elems = 512 max < 1023. Safe.
__device__ __forceinline__ unsigned int pack32(float p, float t) {
    unsigned int sp = (p != 0.0f) ? 1u : 0u;
    unsigned int st = (t != 0.0f) ? 1u : 0u;
    return ((sp & st) << 20) | (sp << 10) | st;
}

__device__ __forceinline__ void accum4(unsigned int (*s_cnt)[NSEG], int copy,
                                       float4 p, float4 t, int4 l) {
    atomicAdd(&s_cnt[copy][l.x], pack32(p.x, t.x));
    atomicAdd(&s_cnt[copy][l.y], pack32(p.y, t.y));
    atomicAdd(&s_cnt[copy][l.z], pack32(p.z, t.z));
    atomicAdd(&s_cnt[copy][l.w], pack32(p.w, t.w));
}

__global__ __launch_bounds__(THREADS, 4) void seg_count_fused_kernel(
    const float* __restrict__ pred,
    const float* __restrict__ target,
    const int* __restrict__ labels,
    unsigned long long* __restrict__ part,   // [NSEG][NREP] packed u64, zeroed
    unsigned int* __restrict__ ticket,       // zeroed
    const int* __restrict__ nc_ptr,
    float* __restrict__ out,
    int n)
{
    __shared__ unsigned int s_cnt[NCOPY][NSEG];   // 4160 B
    __shared__ float s_dice[64];
    __shared__ unsigned int s_last;
    const int tid = threadIdx.x;
    const int copy = tid >> 4;
    const int rep = (int)blockIdx.x & REP_MASK;

    for (int i = tid; i < NCOPY * NSEG; i += THREADS)
        ((unsigned int*)s_cnt)[i] = 0u;
    __syncthreads();

    const int n_vec = n >> 2;  // float4 groups
    const float4* __restrict__ p4 = (const float4*)pred;
    const float4* __restrict__ t4 = (const float4*)target;
    const int4*   __restrict__ l4 = (const int4*)labels;

    // contiguous chunk per block: 2048 groups -> 8 per thread, one batch.
    const int chunk = (n_vec + (int)gridDim.x - 1) / (int)gridDim.x;
    const int base = blockIdx.x * chunk;
    const int end = min(base + chunk, n_vec);

    // R5's exact best-measured loop (72.8 us): UNROLL-8 batched loads
    // (fully-unrolled static-index arrays -> registers, rule #20 ok),
    // then 8 accum groups.
    int idx = base + tid;
    for (; idx + (UNROLL - 1) * THREADS < end; idx += UNROLL * THREADS) {
        float4 p[UNROLL]; float4 t[UNROLL]; int4 l[UNROLL];
        #pragma unroll
        for (int u = 0; u < UNROLL; ++u) p[u] = p4[idx + u * THREADS];
        #pragma unroll
        for (int u = 0; u < UNROLL; ++u) t[u] = t4[idx + u * THREADS];
        #pragma unroll
        for (int u = 0; u < UNROLL; ++u) l[u] = l4[idx + u * THREADS];
        __builtin_amdgcn_sched_barrier(0);
        #pragma unroll
        for (int u = 0; u < UNROLL; ++u) accum4(s_cnt, copy, p[u], t[u], l[u]);
    }
    for (; idx < end; idx += THREADS)
        accum4(s_cnt, copy, p4[idx], t4[idx], l4[idx]);

    // scalar tail (n not divisible by 4): block 0 only
    if (blockIdx.x == 0) {
        for (int i = (n_vec << 2) + tid; i < n; i += THREADS)
            atomicAdd(&s_cnt[copy][labels[i]], pack32(pred[i], target[i]));
    }
    __syncthreads();

    // fold 16 u32 copies -> one packed u64 global atomic per segment into
    // this block's replica. Per-replica field bound: 32 blocks x 8192 =
    // 262k < 2^21. Safe.
    for (int s = tid; s < NSEG; s += THREADS) {
        unsigned long long in = 0, sp = 0, st = 0;
        #pragma unroll
        for (int c = 0; c < NCOPY; ++c) {
            unsigned int v = s_cnt[c][s];
            st += v & 0x3FFu;
            sp += (v >> 10) & 0x3FFu;
            in += v >> 20;
        }
        unsigned long long tot = (in << 42) | (sp << 21) | st;
        if (tot) atomicAdd(&part[s * NREP + rep], tot);
    }

    // ---- last-block finalize (proven correct in R11) ----
    __threadfence();                 // publish this block's part[] atomics
    __syncthreads();
    if (tid == 0)
        s_last = (atomicAdd(ticket, 1u) == (unsigned int)gridDim.x - 1u) ? 1u : 0u;
    __syncthreads();
    if (s_last) {
        __threadfence();             // acquire side
        const int nc = *nc_ptr;      // 64
        const int s = 1 + (tid >> 2);    // 4 threads per segment, 1..64
        const int q = tid & 3;
        unsigned long long acc = 0;
        unsigned long long* row = part + s * NREP + q * 16;
        #pragma unroll
        for (int i = 0; i < 16; ++i)
            acc += atomicAdd(&row[i], 0ull);   // device-scope coherent read
        acc += __shfl_xor(acc, 1);
        acc += __shfl_xor(acc, 2);
        if (q == 0) {
            float in = (float)(acc >> 42);
            float sp = (float)((acc >> 21) & 0x1FFFFFull);
            float st = (float)(acc & 0x1FFFFFull);
            float uni = sp + st;
            float dice = (uni > 0.0f) ? (2.0f * in / uni) : 1.0f;
            s_dice[s - 1] = (s <= nc) ? dice : 0.0f;
        }
        __syncthreads();
        if (tid < 64) {
            float local = s_dice[tid];
            #pragma unroll
            for (int off = 32; off > 0; off >>= 1)
                local += __shfl_down(local, off);
            if (tid == 0) out[0] = 1.0f - local / (float)nc;
        }
    }
}

extern "C" void kernel_launch(void* const* d_in, const int* in_sizes, int n_in,
                              void* d_out, int out_size, void* d_ws, size_t ws_size,
                              hipStream_t stream) {
    const float* pred   = (const float*)d_in[0];
    const float* target = (const float*)d_in[1];
    const int*   labels = (const int*)d_in[2];
    const int*   nc_ptr = (const int*)d_in[3];
    float* out = (float*)d_out;
    unsigned long long* part = (unsigned long long*)d_ws;
    unsigned int* ticket = (unsigned int*)((char*)d_ws + NSEG * NREP * 8);

    const int n = in_sizes[0];

    hipMemsetAsync(d_ws, 0, NSEG * NREP * 8 + 16, stream);

    seg_count_fused_kernel<<<BLOCKS, THREADS, 0, stream>>>(
        pred, target, labels, part, ticket, nc_ptr, out, n);
}